// Round 3
// baseline (623.383 us; speedup 1.0000x reference)
//
#include <hip/hip_runtime.h>
#include <math.h>
#include <stdint.h>

// ---------------------------------------------------------------------------
// MalaAttention on MI355X (gfx950). Round 3: RoPE fused into proj-GEMM
// epilogue (sin/cos table); mala-epilogue+LePE+gate fused into num-GEMM
// epilogue (P buffer eliminated); merged prep kernel; 7 launches total.
//
// Workspace layout (bytes):
//   Xb    @ 0          32MB  bf16 X        (dead after proj -> kvp/ksump/vsump)
//   kvp   @ 0          16MB  f32 [8][bh][128][128] kv partials
//   ksump @ 16777216  128KB  f32 [8][bh][128]
//   vsump @ 16908288  128KB  f32 [8][bh][128]
//   Wcat  @ 33554432    8MB  bf16 [Wq;Wk;Wv;Wg]
//   Wob   @ 41943040    2MB  bf16 Wo
//   tab   @ 44040192    2MB  float2 [4096][64] rope sin/cos
//   QKVG  @ 46137344  128MB  bf16 [16384][4096] col blocks: q|k|v|g
//   ksum  @ 180355072  16KB  f32 [bh][128]
//   vsum  @ 180371456  16KB  f32 [bh][128]
//   kvT   @ 180387840   1MB  bf16 kvT[bh][e][d]
//   den   @ 181436416 512KB  f32 [16384][8]
//   obuf  @ 181960704  32MB  bf16 gated out
//   total 215515136 (same high-water as round 1)
// ---------------------------------------------------------------------------

typedef __bf16 bf16;
typedef __bf16 bf16x2 __attribute__((ext_vector_type(2)));
typedef __bf16 bf16x4 __attribute__((ext_vector_type(4)));
typedef __bf16 bf16x8 __attribute__((ext_vector_type(8)));
typedef float f32x4 __attribute__((ext_vector_type(4)));

static constexpr float kScale = 0.08838834764831845f; // 1/sqrt(128)

__device__ __forceinline__ void async_copy16(const void* g, void* l) {
  __builtin_amdgcn_global_load_lds(
      (const __attribute__((address_space(1))) void*)(uintptr_t)g,
      (__attribute__((address_space(3))) void*)(uintptr_t)l, 16, 0, 0);
}

// ---------------------------------------------------------------------------
// Proj GEMM: QKVG = Xb @ Wcat^T, with RoPE applied in-epilogue for q,k tiles
// (blockIdx.y < 16). Tile 128x128, BK=32, 4 waves, 64x64 quadrant per wave.
// ---------------------------------------------------------------------------
__global__ __launch_bounds__(256, 2) void gemm_qkvg(
    const bf16* __restrict__ A, const bf16* __restrict__ Bw,
    bf16* __restrict__ C, const float2* __restrict__ tab)
{
  __shared__ __align__(16) char smem[34816];   // max(As+Bs=16K, T=128*136*2)
  bf16* As = (bf16*)smem;
  bf16* Bs = (bf16*)(smem + 8192);
  bf16* T  = (bf16*)smem;                      // epilogue tile, stride 136

  const int t = threadIdx.x;
  const long m0 = (long)blockIdx.x * 128;
  A  += m0 * 1024;
  Bw += (long)blockIdx.y * 131072;             // 128 rows x 1024
  C  += m0 * 4096 + (long)blockIdx.y * 128;

  const int i0 = t, i1 = t + 256;
  const bf16* gA0 = A  + (long)(i0 >> 2) * 1024 + (i0 & 3) * 8;
  const bf16* gA1 = A  + (long)(i1 >> 2) * 1024 + (i1 & 3) * 8;
  const bf16* gB0 = Bw + (long)(i0 >> 2) * 1024 + (i0 & 3) * 8;
  const bf16* gB1 = Bw + (long)(i1 >> 2) * 1024 + (i1 & 3) * 8;
  bf16* lA0 = As + i0 * 8; bf16* lA1 = As + i1 * 8;
  bf16* lB0 = Bs + i0 * 8; bf16* lB1 = Bs + i1 * 8;

  const int lane = t & 63, wv = t >> 6;
  const int moff = (wv & 1) * 64, noff = (wv >> 1) * 64;
  const int fm = lane & 15, fq = lane >> 4;

  f32x4 acc[4][4] = {};

  for (int k0 = 0; k0 < 1024; k0 += 32) {
    async_copy16(gA0, lA0); async_copy16(gA1, lA1);
    async_copy16(gB0, lB0); async_copy16(gB1, lB1);
    gA0 += 32; gA1 += 32; gB0 += 32; gB1 += 32;
    __syncthreads();
    bf16x8 af[4], bfv[4];
#pragma unroll
    for (int i = 0; i < 4; ++i) {
      af[i]  = *(const bf16x8*)(As + (moff + i * 16 + fm) * 32 + fq * 8);
      bfv[i] = *(const bf16x8*)(Bs + (noff + i * 16 + fm) * 32 + fq * 8);
    }
#pragma unroll
    for (int i = 0; i < 4; ++i)
#pragma unroll
      for (int j = 0; j < 4; ++j)
        acc[i][j] = __builtin_amdgcn_mfma_f32_16x16x32_bf16(af[i], bfv[j], acc[i][j], 0, 0, 0);
    __syncthreads();
  }

  if (blockIdx.y < 16) {
    // q/k tile: RoPE via LDS round-trip. (last loop stmt was __syncthreads)
#pragma unroll
    for (int i = 0; i < 4; ++i)
#pragma unroll
      for (int j = 0; j < 4; ++j)
#pragma unroll
        for (int r = 0; r < 4; ++r)
          T[(moff + i * 16 + fq * 4 + r) * 136 + noff + j * 16 + fm] = (bf16)acc[i][j][r];
    __syncthreads();
#pragma unroll
    for (int it = 0; it < 32; ++it) {
      const int pi = t + it * 256;           // 8192 pairs
      const int row = pi >> 6, i = pi & 63;
      const int s = (int)((m0 + row) & 4095);
      const float2 sc = tab[s * 64 + i];     // {sin, cos}
      float x1 = (float)T[row * 136 + i];
      float x2 = (float)T[row * 136 + i + 64];
      T[row * 136 + i]      = (bf16)(x1 * sc.y - x2 * sc.x);
      T[row * 136 + i + 64] = (bf16)(x2 * sc.y + x1 * sc.x);
    }
    __syncthreads();
    const int row = t >> 1, c0 = (t & 1) * 64;
    bf16* dst = C + (long)row * 4096 + c0;
    const bf16* src = T + row * 136 + c0;
#pragma unroll
    for (int j2 = 0; j2 < 8; ++j2)
      *(bf16x8*)(dst + j2 * 8) = *(const bf16x8*)(src + j2 * 8);
  } else {
#pragma unroll
    for (int i = 0; i < 4; ++i)
#pragma unroll
      for (int j = 0; j < 4; ++j)
#pragma unroll
        for (int r = 0; r < 4; ++r)
          C[(long)(moff + i * 16 + fq * 4 + r) * 4096 + noff + j * 16 + fm] = (bf16)acc[i][j][r];
  }
}

// ---------------------------------------------------------------------------
// Generic NT GEMM (final projection): C = A @ B^T, fp32 out.
// ---------------------------------------------------------------------------
__global__ __launch_bounds__(256, 2) void gemm_final(
    const bf16* __restrict__ A, const bf16* __restrict__ Bw,
    float* __restrict__ C)
{
  __shared__ __align__(16) bf16 As[128 * 32];
  __shared__ __align__(16) bf16 Bs[128 * 32];
  const int t = threadIdx.x;
  const long m0 = (long)blockIdx.x * 128;
  A  += m0 * 1024;
  Bw += (long)blockIdx.y * 131072;
  C  += m0 * 1024 + (long)blockIdx.y * 128;

  const int i0 = t, i1 = t + 256;
  const bf16* gA0 = A  + (long)(i0 >> 2) * 1024 + (i0 & 3) * 8;
  const bf16* gA1 = A  + (long)(i1 >> 2) * 1024 + (i1 & 3) * 8;
  const bf16* gB0 = Bw + (long)(i0 >> 2) * 1024 + (i0 & 3) * 8;
  const bf16* gB1 = Bw + (long)(i1 >> 2) * 1024 + (i1 & 3) * 8;
  bf16* lA0 = As + i0 * 8; bf16* lA1 = As + i1 * 8;
  bf16* lB0 = Bs + i0 * 8; bf16* lB1 = Bs + i1 * 8;

  const int lane = t & 63, wv = t >> 6;
  const int moff = (wv & 1) * 64, noff = (wv >> 1) * 64;
  const int fm = lane & 15, fq = lane >> 4;

  f32x4 acc[4][4] = {};

  for (int k0 = 0; k0 < 1024; k0 += 32) {
    async_copy16(gA0, lA0); async_copy16(gA1, lA1);
    async_copy16(gB0, lB0); async_copy16(gB1, lB1);
    gA0 += 32; gA1 += 32; gB0 += 32; gB1 += 32;
    __syncthreads();
    bf16x8 af[4], bfv[4];
#pragma unroll
    for (int i = 0; i < 4; ++i) {
      af[i]  = *(const bf16x8*)(As + (moff + i * 16 + fm) * 32 + fq * 8);
      bfv[i] = *(const bf16x8*)(Bs + (noff + i * 16 + fm) * 32 + fq * 8);
    }
#pragma unroll
    for (int i = 0; i < 4; ++i)
#pragma unroll
      for (int j = 0; j < 4; ++j)
        acc[i][j] = __builtin_amdgcn_mfma_f32_16x16x32_bf16(af[i], bfv[j], acc[i][j], 0, 0, 0);
    __syncthreads();
  }

#pragma unroll
  for (int i = 0; i < 4; ++i)
#pragma unroll
    for (int j = 0; j < 4; ++j)
#pragma unroll
      for (int r = 0; r < 4; ++r)
        C[(long)(moff + i * 16 + fq * 4 + r) * 1024 + noff + j * 16 + fm] = acc[i][j][r];
}

// ---------------------------------------------------------------------------
// num GEMM (per b,h: M=4096 N=128 K=128) with fused mala+LePE+gate epilogue.
// A = roped q, B = kvT[bh]. Writes obuf bf16 directly; no P buffer.
// ---------------------------------------------------------------------------
__global__ __launch_bounds__(256, 2) void gemm_num(
    const bf16* __restrict__ QKVG, const bf16* __restrict__ kvTall,
    const float* __restrict__ den, const float* __restrict__ vsum,
    const float* __restrict__ lepe_w, const float* __restrict__ lepe_b,
    bf16* __restrict__ obuf)
{
  __shared__ __align__(16) char smem[34816];
  bf16* As = (bf16*)smem;
  bf16* Bs = (bf16*)(smem + 8192);
  bf16* T  = (bf16*)smem;                      // epilogue, stride 136
  __shared__ float sden[128], svsum[128], slb[128];
  __shared__ float slw[128 * 5];

  const int t = threadIdx.x;
  const int h = blockIdx.y, b = blockIdx.z;
  const long m0 = (long)blockIdx.x * 128;      // s offset within batch
  const bf16* A  = QKVG + (long)b * 16777216 + m0 * 4096 + h * 128;
  const bf16* Bw = kvTall + ((long)(b * 8 + h)) * 16384;

  // stage epilogue params (ready before first sync)
  if (t < 128) {
    sden[t]  = den[((long)b * 4096 + m0 + t) * 8 + h];
    svsum[t] = vsum[(b * 8 + h) * 128 + t];
    slb[t]   = lepe_b[h * 128 + t];
#pragma unroll
    for (int j = 0; j < 5; ++j) slw[t * 5 + j] = lepe_w[(h * 128 + t) * 5 + j];
  }

  const int i0 = t, i1 = t + 256;
  const bf16* gA0 = A + (long)(i0 >> 2) * 4096 + (i0 & 3) * 8;
  const bf16* gA1 = A + (long)(i1 >> 2) * 4096 + (i1 & 3) * 8;
  const bf16* gB0 = Bw + (long)(i0 >> 2) * 128 + (i0 & 3) * 8;
  const bf16* gB1 = Bw + (long)(i1 >> 2) * 128 + (i1 & 3) * 8;
  bf16* lA0 = As + i0 * 8; bf16* lA1 = As + i1 * 8;
  bf16* lB0 = Bs + i0 * 8; bf16* lB1 = Bs + i1 * 8;

  const int lane = t & 63, wv = t >> 6;
  const int moff = (wv & 1) * 64, noff = (wv >> 1) * 64;
  const int fm = lane & 15, fq = lane >> 4;

  f32x4 acc[4][4] = {};

  for (int k0 = 0; k0 < 128; k0 += 32) {
    async_copy16(gA0, lA0); async_copy16(gA1, lA1);
    async_copy16(gB0, lB0); async_copy16(gB1, lB1);
    gA0 += 32; gA1 += 32; gB0 += 32; gB1 += 32;
    __syncthreads();
    bf16x8 af[4], bfv[4];
#pragma unroll
    for (int i = 0; i < 4; ++i) {
      af[i]  = *(const bf16x8*)(As + (moff + i * 16 + fm) * 32 + fq * 8);
      bfv[i] = *(const bf16x8*)(Bs + (noff + i * 16 + fm) * 32 + fq * 8);
    }
#pragma unroll
    for (int i = 0; i < 4; ++i)
#pragma unroll
      for (int j = 0; j < 4; ++j)
        acc[i][j] = __builtin_amdgcn_mfma_f32_16x16x32_bf16(af[i], bfv[j], acc[i][j], 0, 0, 0);
    __syncthreads();
  }

  // attn value -> LDS tile (bf16, same precision as old P path)
#pragma unroll
  for (int i = 0; i < 4; ++i)
#pragma unroll
    for (int j = 0; j < 4; ++j)
#pragma unroll
      for (int r = 0; r < 4; ++r) {
        const int row = moff + i * 16 + fq * 4 + r;
        const int col = noff + j * 16 + fm;
        T[row * 136 + col] = (bf16)((acc[i][j][r] * kScale + svsum[col]) / sden[row]);
      }
  __syncthreads();

  // row phase: +LePE, *gate, write obuf
  const int row = t >> 1, c0 = (t & 1) * 64;
  const int s = (int)(m0 + row);               // s within batch [0,4096)
  const long grow = (long)b * 4096 + s;
  const bf16* vbase = QKVG + grow * 4096 + 2048 + h * 128;
  const bf16* gbase = QKVG + grow * 4096 + 3072 + h * 128;
  bf16* obase = obuf + grow * 1024 + h * 128;
#pragma unroll
  for (int cb = 0; cb < 8; ++cb) {
    const int c = c0 + cb * 8;
    bf16x8 a8 = *(const bf16x8*)(T + row * 136 + c);
    bf16x8 g8 = *(const bf16x8*)(gbase + c);
    float lep[8];
#pragma unroll
    for (int e = 0; e < 8; ++e) lep[e] = slb[c + e];
#pragma unroll
    for (int jt = 0; jt < 5; ++jt) {
      const int srow = s + jt - 2;
      if (srow >= 0 && srow < 4096) {
        bf16x8 v8 = *(const bf16x8*)(vbase + (long)(jt - 2) * 4096 + c);
#pragma unroll
        for (int e = 0; e < 8; ++e) lep[e] += (float)v8[e] * slw[(c + e) * 5 + jt];
      }
    }
    bf16x8 o8;
#pragma unroll
    for (int e = 0; e < 8; ++e)
      o8[e] = (bf16)(((float)a8[e] + lep[e]) * (float)g8[e]);
    *(bf16x8*)(obase + c) = o8;
  }
}

// ---------------------------------------------------------------------------
// prep: cast X->bf16, cast/concat weights, build rope sin/cos table.
// ---------------------------------------------------------------------------
__global__ void prep_kernel(const float* __restrict__ X, const float* __restrict__ Wq,
                            const float* __restrict__ Wk, const float* __restrict__ Wv,
                            const float* __restrict__ Wg, const float* __restrict__ Wo,
                            bf16* __restrict__ Xb, bf16* __restrict__ Wcat,
                            bf16* __restrict__ Wob, float2* __restrict__ tab)
{
  const int blk = blockIdx.x;
  if (blk < 16384) {
    long g = ((long)blk * 256 + threadIdx.x) * 4;
    float4 v = *(const float4*)(X + g);
    bf16x4 o = {(bf16)v.x, (bf16)v.y, (bf16)v.z, (bf16)v.w};
    *(bf16x4*)(Xb + g) = o;
  } else if (blk < 21504) {
    long g = ((long)(blk - 16384) * 256 + threadIdx.x) * 4;
    if (g < 4194304) {
      long idx = g & 1048575;
      int sel = (int)(g >> 20);
      const float* s = sel == 0 ? Wq : sel == 1 ? Wk : sel == 2 ? Wv : Wg;
      float4 v = *(const float4*)(s + idx);
      bf16x4 o = {(bf16)v.x, (bf16)v.y, (bf16)v.z, (bf16)v.w};
      *(bf16x4*)(Wcat + g) = o;
    } else {
      long idx = g - 4194304;
      float4 v = *(const float4*)(Wo + idx);
      bf16x4 o = {(bf16)v.x, (bf16)v.y, (bf16)v.z, (bf16)v.w};
      *(bf16x4*)(Wob + idx) = o;
    }
  } else {
    int idx = (blk - 21504) * 256 + threadIdx.x;   // [0, 262144)
    int s = idx >> 6, i = idx & 63;
    float inv = powf(10000.0f, -((float)(2 * i)) / 128.0f);
    float ang = (float)s * inv;
    float sn, cs;
    sincosf(ang, &sn, &cs);
    tab[idx] = make_float2(sn, cs);
  }
}

// ---------------------------------------------------------------------------
// kv via MFMA with in-LDS transpose. Grid (8 s-chunks, 32 bh). No atomics.
// kvp[chunk][bh][e][d] = sum_s v[s][e] k[s][d]; + ksum/vsum partials.
// ---------------------------------------------------------------------------
__global__ __launch_bounds__(256, 2) void kv_mfma(
    const bf16* __restrict__ QKVG, float* __restrict__ kvp,
    float* __restrict__ ksump, float* __restrict__ vsump)
{
  __shared__ __align__(16) bf16 VT[128 * 40];
  __shared__ __align__(16) bf16 KT[128 * 40];
  const int t = threadIdx.x;
  const int chunk = blockIdx.x, bh = blockIdx.y;
  const int b = bh >> 3, h = bh & 7;
  const long rowbase = ((long)b * 4096 + chunk * 512) * 4096 + h * 128;
  const bf16* Kg = QKVG + rowbase + 1024;
  const bf16* Vg = QKVG + rowbase + 2048;

  const int sp = t >> 4, fc = t & 15;
  const int lane = t & 63, wv = t >> 6;
  const int eoff = (wv & 1) * 64, doff = (wv >> 1) * 64;
  const int fm = lane & 15, fq = lane >> 4;
  const int srow = t & 127;
  const bool sumK = t >= 128;

  f32x4 acc[4][4] = {};
  float rsum = 0.f;

  for (int sb = 0; sb < 512; sb += 32) {
    const long go = (long)(sb + 2 * sp) * 4096 + fc * 8;
    bf16x8 v0 = *(const bf16x8*)(Vg + go);
    bf16x8 v1 = *(const bf16x8*)(Vg + go + 4096);
    bf16x8 k0 = *(const bf16x8*)(Kg + go);
    bf16x8 k1 = *(const bf16x8*)(Kg + go + 4096);
#pragma unroll
    for (int j = 0; j < 8; ++j) {
      const int f = fc * 8 + j;
      bf16x2 vp2 = {v0[j], v1[j]};
      bf16x2 kp2 = {k0[j], k1[j]};
      *(bf16x2*)(VT + f * 40 + 2 * sp) = vp2;
      *(bf16x2*)(KT + f * 40 + 2 * sp) = kp2;
    }
    __syncthreads();
    bf16x8 af[4], bfv[4];
#pragma unroll
    for (int i = 0; i < 4; ++i) {
      af[i]  = *(const bf16x8*)(VT + (eoff + i * 16 + fm) * 40 + fq * 8);
      bfv[i] = *(const bf16x8*)(KT + (doff + i * 16 + fm) * 40 + fq * 8);
    }
#pragma unroll
    for (int i = 0; i < 4; ++i)
#pragma unroll
      for (int j = 0; j < 4; ++j)
        acc[i][j] = __builtin_amdgcn_mfma_f32_16x16x32_bf16(af[i], bfv[j], acc[i][j], 0, 0, 0);
    const bf16* rp = (sumK ? KT : VT) + srow * 40;
#pragma unroll
    for (int i = 0; i < 4; ++i) {
      bf16x8 r8 = *(const bf16x8*)(rp + i * 8);
#pragma unroll
      for (int j = 0; j < 8; ++j) rsum += (float)r8[j];
    }
    __syncthreads();
  }

  float* plane = kvp + ((long)chunk * 32 + bh) * 16384;
#pragma unroll
  for (int i = 0; i < 4; ++i)
#pragma unroll
    for (int j = 0; j < 4; ++j)
#pragma unroll
      for (int r = 0; r < 4; ++r)
        plane[(long)(eoff + i * 16 + fq * 4 + r) * 128 + (doff + j * 16 + fm)] = acc[i][j][r];
  float* sdst = (sumK ? ksump : vsump) + ((long)chunk * 32 + bh) * 128 + srow;
  *sdst = rsum;
}

// Fold 8 chunk partials -> bf16 kvT + f32 ksum/vsum.
__global__ void kv_reduce(const float* __restrict__ kvp, const float* __restrict__ ksump,
                          const float* __restrict__ vsump, bf16* __restrict__ kvT,
                          float* __restrict__ ksum, float* __restrict__ vsum)
{
  long g = (long)blockIdx.x * 256 + threadIdx.x;  // 524288
  long bh = g >> 14, idx = g & 16383;
  float s = 0.f;
#pragma unroll
  for (int c = 0; c < 8; ++c) s += kvp[((long)c * 32 + bh) * 16384 + idx];
  kvT[g] = (bf16)s;
  if (g < 8192) {
    int bh2 = (int)(g >> 8), rem = (int)(g & 255), f = rem & 127;
    const float* src = (rem >> 7) ? ksump : vsump;
    float* dst = (rem >> 7) ? ksum : vsum;
    float s2 = 0.f;
#pragma unroll
    for (int c = 0; c < 8; ++c) s2 += src[((long)c * 32 + bh2) * 128 + f];
    dst[bh2 * 128 + f] = s2;
  }
}

// den[r][h] = scale * q[r,h,:].ksum[b,h,:] + S ; one wave per (r,h).
__global__ void den_kernel(const bf16* __restrict__ QKVG, const float* __restrict__ ksum,
                           float* __restrict__ den)
{
  const int t = threadIdx.x, lane = t & 63;
  const long gw = (long)blockIdx.x * 4 + (t >> 6);  // 131072 waves
  const long r = gw >> 3;
  const int h = (int)(gw & 7);
  const int b = (int)(r >> 12);
  bf16x2 q2 = *(const bf16x2*)(QKVG + r * 4096 + h * 128 + lane * 2);
  float2 k2 = *(const float2*)(ksum + (b * 8 + h) * 128 + lane * 2);
  float p = (float)q2[0] * k2.x + (float)q2[1] * k2.y;
#pragma unroll
  for (int o = 32; o > 0; o >>= 1) p += __shfl_xor(p, o, 64);
  if (lane == 0) den[r * 8 + h] = p * kScale + 4096.0f;
}

// ---------------------------------------------------------------------------
extern "C" void kernel_launch(void* const* d_in, const int* in_sizes, int n_in,
                              void* d_out, int out_size, void* d_ws, size_t ws_size,
                              hipStream_t stream)
{
  const float* X      = (const float*)d_in[0];
  const float* Wq     = (const float*)d_in[1];
  const float* Wk     = (const float*)d_in[2];
  const float* Wv     = (const float*)d_in[3];
  const float* Wg     = (const float*)d_in[4];
  const float* Wo     = (const float*)d_in[5];
  const float* lepe_w = (const float*)d_in[6];
  const float* lepe_b = (const float*)d_in[7];
  float* out = (float*)d_out;

  char* ws = (char*)d_ws;
  bf16*   Xb    = (bf16*)(ws);
  float*  kvp   = (float*)(ws);                  // aliases Xb (dead after proj)
  float*  ksump = (float*)(ws + 16777216);
  float*  vsump = (float*)(ws + 16908288);
  bf16*   Wcat  = (bf16*)(ws + 33554432);
  bf16*   Wob   = (bf16*)(ws + 41943040);
  float2* tab   = (float2*)(ws + 44040192);
  bf16*   QKVG  = (bf16*)(ws + 46137344);
  float*  ksum  = (float*)(ws + 180355072);
  float*  vsum  = (float*)(ws + 180371456);
  bf16*   kvT   = (bf16*)(ws + 180387840);
  float*  den   = (float*)(ws + 181436416);
  bf16*   obuf  = (bf16*)(ws + 181960704);

  prep_kernel<<<22528, 256, 0, stream>>>(X, Wq, Wk, Wv, Wg, Wo, Xb, Wcat, Wob, tab);

  // QKVG = Xb @ Wcat^T (RoPE fused for y<16): M=16384 N=4096 K=1024
  gemm_qkvg<<<dim3(128, 32), 256, 0, stream>>>(Xb, Wcat, QKVG, tab);

  kv_mfma<<<dim3(8, 32), 256, 0, stream>>>(QKVG, kvp, ksump, vsump);
  kv_reduce<<<2048, 256, 0, stream>>>(kvp, ksump, vsump, kvT, ksum, vsum);
  den_kernel<<<32768, 256, 0, stream>>>(QKVG, ksum, den);

  // num GEMM + fused mala/LePE/gate epilogue -> obuf
  gemm_num<<<dim3(32, 8, 4), 256, 0, stream>>>(QKVG, kvT, den, vsum, lepe_w, lepe_b, obuf);

  // out = obuf @ Wob^T : M=16384 N=1024 K=1024, fp32 out
  gemm_final<<<dim3(128, 8), 256, 0, stream>>>(obuf, Wob, out);
}

// Round 4
// 524.105 us; speedup vs baseline: 1.1894x; 1.1894x over previous
//
#include <hip/hip_runtime.h>
#include <math.h>
#include <stdint.h>

// ---------------------------------------------------------------------------
// MalaAttention on MI355X (gfx950). Round 4: round-3 fusions kept; gemm_num
// epilogue access pattern fixed (coalesced per-row wave reads; was 32-rows-
// strided 16B/line -> 512MB overfetch). den transposed to [bh][s]; slw [tap][c].
//
// Workspace layout (bytes):
//   Xb    @ 0          32MB  bf16 X        (dead after proj -> kvp/ksump/vsump)
//   kvp   @ 0          16MB  f32 [8][bh][128][128] kv partials
//   ksump @ 16777216  128KB  f32 [8][bh][128]
//   vsump @ 16908288  128KB  f32 [8][bh][128]
//   Wcat  @ 33554432    8MB  bf16 [Wq;Wk;Wv;Wg]
//   Wob   @ 41943040    2MB  bf16 Wo
//   tab   @ 44040192    2MB  float2 [4096][64] rope sin/cos
//   QKVG  @ 46137344  128MB  bf16 [16384][4096] col blocks: q|k|v|g
//   ksum  @ 180355072  16KB  f32 [bh][128]
//   vsum  @ 180371456  16KB  f32 [bh][128]
//   kvT   @ 180387840   1MB  bf16 kvT[bh][e][d]
//   den   @ 181436416 512KB  f32 [bh][4096]  (TRANSPOSED this round)
//   obuf  @ 181960704  32MB  bf16 gated out
// ---------------------------------------------------------------------------

typedef __bf16 bf16;
typedef __bf16 bf16x2 __attribute__((ext_vector_type(2)));
typedef __bf16 bf16x4 __attribute__((ext_vector_type(4)));
typedef __bf16 bf16x8 __attribute__((ext_vector_type(8)));
typedef float f32x4 __attribute__((ext_vector_type(4)));

static constexpr float kScale = 0.08838834764831845f; // 1/sqrt(128)

__device__ __forceinline__ void async_copy16(const void* g, void* l) {
  __builtin_amdgcn_global_load_lds(
      (const __attribute__((address_space(1))) void*)(uintptr_t)g,
      (__attribute__((address_space(3))) void*)(uintptr_t)l, 16, 0, 0);
}

// ---------------------------------------------------------------------------
// Proj GEMM: QKVG = Xb @ Wcat^T, RoPE fused in-epilogue for q,k (y<16).
// ---------------------------------------------------------------------------
__global__ __launch_bounds__(256, 2) void gemm_qkvg(
    const bf16* __restrict__ A, const bf16* __restrict__ Bw,
    bf16* __restrict__ C, const float2* __restrict__ tab)
{
  __shared__ __align__(16) char smem[34816];   // max(As+Bs=16K, T=128*136*2)
  bf16* As = (bf16*)smem;
  bf16* Bs = (bf16*)(smem + 8192);
  bf16* T  = (bf16*)smem;                      // epilogue tile, stride 136

  const int t = threadIdx.x;
  const long m0 = (long)blockIdx.x * 128;
  A  += m0 * 1024;
  Bw += (long)blockIdx.y * 131072;
  C  += m0 * 4096 + (long)blockIdx.y * 128;

  const int i0 = t, i1 = t + 256;
  const bf16* gA0 = A  + (long)(i0 >> 2) * 1024 + (i0 & 3) * 8;
  const bf16* gA1 = A  + (long)(i1 >> 2) * 1024 + (i1 & 3) * 8;
  const bf16* gB0 = Bw + (long)(i0 >> 2) * 1024 + (i0 & 3) * 8;
  const bf16* gB1 = Bw + (long)(i1 >> 2) * 1024 + (i1 & 3) * 8;
  bf16* lA0 = As + i0 * 8; bf16* lA1 = As + i1 * 8;
  bf16* lB0 = Bs + i0 * 8; bf16* lB1 = Bs + i1 * 8;

  const int lane = t & 63, wv = t >> 6;
  const int moff = (wv & 1) * 64, noff = (wv >> 1) * 64;
  const int fm = lane & 15, fq = lane >> 4;

  f32x4 acc[4][4] = {};

  for (int k0 = 0; k0 < 1024; k0 += 32) {
    async_copy16(gA0, lA0); async_copy16(gA1, lA1);
    async_copy16(gB0, lB0); async_copy16(gB1, lB1);
    gA0 += 32; gA1 += 32; gB0 += 32; gB1 += 32;
    __syncthreads();
    bf16x8 af[4], bfv[4];
#pragma unroll
    for (int i = 0; i < 4; ++i) {
      af[i]  = *(const bf16x8*)(As + (moff + i * 16 + fm) * 32 + fq * 8);
      bfv[i] = *(const bf16x8*)(Bs + (noff + i * 16 + fm) * 32 + fq * 8);
    }
#pragma unroll
    for (int i = 0; i < 4; ++i)
#pragma unroll
      for (int j = 0; j < 4; ++j)
        acc[i][j] = __builtin_amdgcn_mfma_f32_16x16x32_bf16(af[i], bfv[j], acc[i][j], 0, 0, 0);
    __syncthreads();
  }

  if (blockIdx.y < 16) {
#pragma unroll
    for (int i = 0; i < 4; ++i)
#pragma unroll
      for (int j = 0; j < 4; ++j)
#pragma unroll
        for (int r = 0; r < 4; ++r)
          T[(moff + i * 16 + fq * 4 + r) * 136 + noff + j * 16 + fm] = (bf16)acc[i][j][r];
    __syncthreads();
#pragma unroll
    for (int it = 0; it < 32; ++it) {
      const int pi = t + it * 256;
      const int row = pi >> 6, i = pi & 63;
      const int s = (int)((m0 + row) & 4095);
      const float2 sc = tab[s * 64 + i];
      float x1 = (float)T[row * 136 + i];
      float x2 = (float)T[row * 136 + i + 64];
      T[row * 136 + i]      = (bf16)(x1 * sc.y - x2 * sc.x);
      T[row * 136 + i + 64] = (bf16)(x2 * sc.y + x1 * sc.x);
    }
    __syncthreads();
    const int row = t >> 1, c0 = (t & 1) * 64;
    bf16* dst = C + (long)row * 4096 + c0;
    const bf16* src = T + row * 136 + c0;
#pragma unroll
    for (int j2 = 0; j2 < 8; ++j2)
      *(bf16x8*)(dst + j2 * 8) = *(const bf16x8*)(src + j2 * 8);
  } else {
#pragma unroll
    for (int i = 0; i < 4; ++i)
#pragma unroll
      for (int j = 0; j < 4; ++j)
#pragma unroll
        for (int r = 0; r < 4; ++r)
          C[(long)(moff + i * 16 + fq * 4 + r) * 4096 + noff + j * 16 + fm] = (bf16)acc[i][j][r];
  }
}

// ---------------------------------------------------------------------------
// Final NT GEMM: out = obuf @ Wo^T, fp32 out.
// ---------------------------------------------------------------------------
__global__ __launch_bounds__(256, 2) void gemm_final(
    const bf16* __restrict__ A, const bf16* __restrict__ Bw,
    float* __restrict__ C)
{
  __shared__ __align__(16) bf16 As[128 * 32];
  __shared__ __align__(16) bf16 Bs[128 * 32];
  const int t = threadIdx.x;
  const long m0 = (long)blockIdx.x * 128;
  A  += m0 * 1024;
  Bw += (long)blockIdx.y * 131072;
  C  += m0 * 1024 + (long)blockIdx.y * 128;

  const int i0 = t, i1 = t + 256;
  const bf16* gA0 = A  + (long)(i0 >> 2) * 1024 + (i0 & 3) * 8;
  const bf16* gA1 = A  + (long)(i1 >> 2) * 1024 + (i1 & 3) * 8;
  const bf16* gB0 = Bw + (long)(i0 >> 2) * 1024 + (i0 & 3) * 8;
  const bf16* gB1 = Bw + (long)(i1 >> 2) * 1024 + (i1 & 3) * 8;
  bf16* lA0 = As + i0 * 8; bf16* lA1 = As + i1 * 8;
  bf16* lB0 = Bs + i0 * 8; bf16* lB1 = Bs + i1 * 8;

  const int lane = t & 63, wv = t >> 6;
  const int moff = (wv & 1) * 64, noff = (wv >> 1) * 64;
  const int fm = lane & 15, fq = lane >> 4;

  f32x4 acc[4][4] = {};

  for (int k0 = 0; k0 < 1024; k0 += 32) {
    async_copy16(gA0, lA0); async_copy16(gA1, lA1);
    async_copy16(gB0, lB0); async_copy16(gB1, lB1);
    gA0 += 32; gA1 += 32; gB0 += 32; gB1 += 32;
    __syncthreads();
    bf16x8 af[4], bfv[4];
#pragma unroll
    for (int i = 0; i < 4; ++i) {
      af[i]  = *(const bf16x8*)(As + (moff + i * 16 + fm) * 32 + fq * 8);
      bfv[i] = *(const bf16x8*)(Bs + (noff + i * 16 + fm) * 32 + fq * 8);
    }
#pragma unroll
    for (int i = 0; i < 4; ++i)
#pragma unroll
      for (int j = 0; j < 4; ++j)
        acc[i][j] = __builtin_amdgcn_mfma_f32_16x16x32_bf16(af[i], bfv[j], acc[i][j], 0, 0, 0);
    __syncthreads();
  }

#pragma unroll
  for (int i = 0; i < 4; ++i)
#pragma unroll
    for (int j = 0; j < 4; ++j)
#pragma unroll
      for (int r = 0; r < 4; ++r)
        C[(long)(moff + i * 16 + fq * 4 + r) * 1024 + noff + j * 16 + fm] = acc[i][j][r];
}

// ---------------------------------------------------------------------------
// num GEMM (per b,h: M=4096 N=128 K=128) + fused mala/LePE/gate epilogue.
// Epilogue: wave w owns rows w*32..+31; 64 lanes cover 128 cols as bf16x2
// -> every global access is a full 256B contiguous wave transaction.
// ---------------------------------------------------------------------------
__global__ __launch_bounds__(256, 2) void gemm_num(
    const bf16* __restrict__ QKVG, const bf16* __restrict__ kvTall,
    const float* __restrict__ den, const float* __restrict__ vsum,
    const float* __restrict__ lepe_w, const float* __restrict__ lepe_b,
    bf16* __restrict__ obuf)
{
  __shared__ __align__(16) char smem[34816];
  bf16* As = (bf16*)smem;
  bf16* Bs = (bf16*)(smem + 8192);
  bf16* T  = (bf16*)smem;                      // epilogue, stride 136
  __shared__ float sden[128], svsum[128], slb[128];
  __shared__ float slw[5][128];                // [tap][col]: stride-1 lanes

  const int t = threadIdx.x;
  const int h = blockIdx.y, b = blockIdx.z;
  const long m0 = (long)blockIdx.x * 128;
  const bf16* A  = QKVG + (long)b * 16777216 + m0 * 4096 + h * 128;
  const bf16* Bw = kvTall + ((long)(b * 8 + h)) * 16384;

  if (t < 128) {
    sden[t]  = den[((long)(b * 8 + h)) * 4096 + m0 + t];   // contiguous
    svsum[t] = vsum[(b * 8 + h) * 128 + t];
    slb[t]   = lepe_b[h * 128 + t];
#pragma unroll
    for (int j = 0; j < 5; ++j) slw[j][t] = lepe_w[(h * 128 + t) * 5 + j];
  }

  const int i0 = t, i1 = t + 256;
  const bf16* gA0 = A + (long)(i0 >> 2) * 4096 + (i0 & 3) * 8;
  const bf16* gA1 = A + (long)(i1 >> 2) * 4096 + (i1 & 3) * 8;
  const bf16* gB0 = Bw + (long)(i0 >> 2) * 128 + (i0 & 3) * 8;
  const bf16* gB1 = Bw + (long)(i1 >> 2) * 128 + (i1 & 3) * 8;
  bf16* lA0 = As + i0 * 8; bf16* lA1 = As + i1 * 8;
  bf16* lB0 = Bs + i0 * 8; bf16* lB1 = Bs + i1 * 8;

  const int lane = t & 63, wv = t >> 6;
  const int moff = (wv & 1) * 64, noff = (wv >> 1) * 64;
  const int fm = lane & 15, fq = lane >> 4;

  f32x4 acc[4][4] = {};

  for (int k0 = 0; k0 < 128; k0 += 32) {
    async_copy16(gA0, lA0); async_copy16(gA1, lA1);
    async_copy16(gB0, lB0); async_copy16(gB1, lB1);
    gA0 += 32; gA1 += 32; gB0 += 32; gB1 += 32;
    __syncthreads();
    bf16x8 af[4], bfv[4];
#pragma unroll
    for (int i = 0; i < 4; ++i) {
      af[i]  = *(const bf16x8*)(As + (moff + i * 16 + fm) * 32 + fq * 8);
      bfv[i] = *(const bf16x8*)(Bs + (noff + i * 16 + fm) * 32 + fq * 8);
    }
#pragma unroll
    for (int i = 0; i < 4; ++i)
#pragma unroll
      for (int j = 0; j < 4; ++j)
        acc[i][j] = __builtin_amdgcn_mfma_f32_16x16x32_bf16(af[i], bfv[j], acc[i][j], 0, 0, 0);
    __syncthreads();
  }

  // attn -> LDS tile (bf16)
#pragma unroll
  for (int i = 0; i < 4; ++i)
#pragma unroll
    for (int j = 0; j < 4; ++j)
#pragma unroll
      for (int r = 0; r < 4; ++r) {
        const int row = moff + i * 16 + fq * 4 + r;
        const int col = noff + j * 16 + fm;
        T[row * 136 + col] = (bf16)((acc[i][j][r] * kScale + svsum[col]) / sden[row]);
      }
  __syncthreads();

  // row phase: coalesced. lane covers cols [lane*2, lane*2+1].
  const int c2 = lane * 2;
  const float w0[5] = {slw[0][c2], slw[1][c2], slw[2][c2], slw[3][c2], slw[4][c2]};
  const float w1[5] = {slw[0][c2+1], slw[1][c2+1], slw[2][c2+1], slw[3][c2+1], slw[4][c2+1]};
  const float lb0 = slb[c2], lb1 = slb[c2 + 1];
  for (int rr = 0; rr < 32; ++rr) {
    const int row = wv * 32 + rr;
    const int s = (int)(m0 + row);
    const long grow = (long)b * 4096 + s;
    const bf16* vrow = QKVG + grow * 4096 + 2048 + h * 128 + c2;
    bf16x2 a2 = *(const bf16x2*)(T + row * 136 + c2);
    float lep0 = lb0, lep1 = lb1;
#pragma unroll
    for (int jt = 0; jt < 5; ++jt) {
      const int srow = s + jt - 2;
      if (srow >= 0 && srow < 4096) {                 // wave-uniform branch
        bf16x2 v2 = *(const bf16x2*)(vrow + (long)(jt - 2) * 4096);
        lep0 += (float)v2[0] * w0[jt];
        lep1 += (float)v2[1] * w1[jt];
      }
    }
    bf16x2 g2 = *(const bf16x2*)(QKVG + grow * 4096 + 3072 + h * 128 + c2);
    bf16x2 o2;
    o2[0] = (bf16)(((float)a2[0] + lep0) * (float)g2[0]);
    o2[1] = (bf16)(((float)a2[1] + lep1) * (float)g2[1]);
    *(bf16x2*)(obuf + grow * 1024 + h * 128 + c2) = o2;
  }
}

// ---------------------------------------------------------------------------
// prep: cast X->bf16, cast/concat weights, build rope sin/cos table.
// ---------------------------------------------------------------------------
__global__ void prep_kernel(const float* __restrict__ X, const float* __restrict__ Wq,
                            const float* __restrict__ Wk, const float* __restrict__ Wv,
                            const float* __restrict__ Wg, const float* __restrict__ Wo,
                            bf16* __restrict__ Xb, bf16* __restrict__ Wcat,
                            bf16* __restrict__ Wob, float2* __restrict__ tab)
{
  const int blk = blockIdx.x;
  if (blk < 16384) {
    long g = ((long)blk * 256 + threadIdx.x) * 4;
    float4 v = *(const float4*)(X + g);
    bf16x4 o = {(bf16)v.x, (bf16)v.y, (bf16)v.z, (bf16)v.w};
    *(bf16x4*)(Xb + g) = o;
  } else if (blk < 21504) {
    long g = ((long)(blk - 16384) * 256 + threadIdx.x) * 4;
    if (g < 4194304) {
      long idx = g & 1048575;
      int sel = (int)(g >> 20);
      const float* s = sel == 0 ? Wq : sel == 1 ? Wk : sel == 2 ? Wv : Wg;
      float4 v = *(const float4*)(s + idx);
      bf16x4 o = {(bf16)v.x, (bf16)v.y, (bf16)v.z, (bf16)v.w};
      *(bf16x4*)(Wcat + g) = o;
    } else {
      long idx = g - 4194304;
      float4 v = *(const float4*)(Wo + idx);
      bf16x4 o = {(bf16)v.x, (bf16)v.y, (bf16)v.z, (bf16)v.w};
      *(bf16x4*)(Wob + idx) = o;
    }
  } else {
    int idx = (blk - 21504) * 256 + threadIdx.x;
    int s = idx >> 6, i = idx & 63;
    float inv = powf(10000.0f, -((float)(2 * i)) / 128.0f);
    float ang = (float)s * inv;
    float sn, cs;
    sincosf(ang, &sn, &cs);
    tab[idx] = make_float2(sn, cs);
  }
}

// ---------------------------------------------------------------------------
// kv via MFMA with in-LDS transpose. Grid (8, 32). No atomics.
// ---------------------------------------------------------------------------
__global__ __launch_bounds__(256, 2) void kv_mfma(
    const bf16* __restrict__ QKVG, float* __restrict__ kvp,
    float* __restrict__ ksump, float* __restrict__ vsump)
{
  __shared__ __align__(16) bf16 VT[128 * 40];
  __shared__ __align__(16) bf16 KT[128 * 40];
  const int t = threadIdx.x;
  const int chunk = blockIdx.x, bh = blockIdx.y;
  const int b = bh >> 3, h = bh & 7;
  const long rowbase = ((long)b * 4096 + chunk * 512) * 4096 + h * 128;
  const bf16* Kg = QKVG + rowbase + 1024;
  const bf16* Vg = QKVG + rowbase + 2048;

  const int sp = t >> 4, fc = t & 15;
  const int lane = t & 63, wv = t >> 6;
  const int eoff = (wv & 1) * 64, doff = (wv >> 1) * 64;
  const int fm = lane & 15, fq = lane >> 4;
  const int srow = t & 127;
  const bool sumK = t >= 128;

  f32x4 acc[4][4] = {};
  float rsum = 0.f;

  for (int sb = 0; sb < 512; sb += 32) {
    const long go = (long)(sb + 2 * sp) * 4096 + fc * 8;
    bf16x8 v0 = *(const bf16x8*)(Vg + go);
    bf16x8 v1 = *(const bf16x8*)(Vg + go + 4096);
    bf16x8 k0 = *(const bf16x8*)(Kg + go);
    bf16x8 k1 = *(const bf16x8*)(Kg + go + 4096);
#pragma unroll
    for (int j = 0; j < 8; ++j) {
      const int f = fc * 8 + j;
      bf16x2 vp2 = {v0[j], v1[j]};
      bf16x2 kp2 = {k0[j], k1[j]};
      *(bf16x2*)(VT + f * 40 + 2 * sp) = vp2;
      *(bf16x2*)(KT + f * 40 + 2 * sp) = kp2;
    }
    __syncthreads();
    bf16x8 af[4], bfv[4];
#pragma unroll
    for (int i = 0; i < 4; ++i) {
      af[i]  = *(const bf16x8*)(VT + (eoff + i * 16 + fm) * 40 + fq * 8);
      bfv[i] = *(const bf16x8*)(KT + (doff + i * 16 + fm) * 40 + fq * 8);
    }
#pragma unroll
    for (int i = 0; i < 4; ++i)
#pragma unroll
      for (int j = 0; j < 4; ++j)
        acc[i][j] = __builtin_amdgcn_mfma_f32_16x16x32_bf16(af[i], bfv[j], acc[i][j], 0, 0, 0);
    const bf16* rp = (sumK ? KT : VT) + srow * 40;
#pragma unroll
    for (int i = 0; i < 4; ++i) {
      bf16x8 r8 = *(const bf16x8*)(rp + i * 8);
#pragma unroll
      for (int j = 0; j < 8; ++j) rsum += (float)r8[j];
    }
    __syncthreads();
  }

  float* plane = kvp + ((long)chunk * 32 + bh) * 16384;
#pragma unroll
  for (int i = 0; i < 4; ++i)
#pragma unroll
    for (int j = 0; j < 4; ++j)
#pragma unroll
      for (int r = 0; r < 4; ++r)
        plane[(long)(eoff + i * 16 + fq * 4 + r) * 128 + (doff + j * 16 + fm)] = acc[i][j][r];
  float* sdst = (sumK ? ksump : vsump) + ((long)chunk * 32 + bh) * 128 + srow;
  *sdst = rsum;
}

// Fold 8 chunk partials -> bf16 kvT + f32 ksum/vsum.
__global__ void kv_reduce(const float* __restrict__ kvp, const float* __restrict__ ksump,
                          const float* __restrict__ vsump, bf16* __restrict__ kvT,
                          float* __restrict__ ksum, float* __restrict__ vsum)
{
  long g = (long)blockIdx.x * 256 + threadIdx.x;
  long bh = g >> 14, idx = g & 16383;
  float s = 0.f;
#pragma unroll
  for (int c = 0; c < 8; ++c) s += kvp[((long)c * 32 + bh) * 16384 + idx];
  kvT[g] = (bf16)s;
  if (g < 8192) {
    int bh2 = (int)(g >> 8), rem = (int)(g & 255), f = rem & 127;
    const float* src = (rem >> 7) ? ksump : vsump;
    float* dst = (rem >> 7) ? ksum : vsum;
    float s2 = 0.f;
#pragma unroll
    for (int c = 0; c < 8; ++c) s2 += src[((long)c * 32 + bh2) * 128 + f];
    dst[bh2 * 128 + f] = s2;
  }
}

// den[bh][s] = scale * q[r,h,:].ksum[b,h,:] + S ; one wave per (r,h).
__global__ void den_kernel(const bf16* __restrict__ QKVG, const float* __restrict__ ksum,
                           float* __restrict__ den)
{
  const int t = threadIdx.x, lane = t & 63;
  const long gw = (long)blockIdx.x * 4 + (t >> 6);
  const long r = gw >> 3;
  const int h = (int)(gw & 7);
  const int b = (int)(r >> 12), s = (int)(r & 4095);
  bf16x2 q2 = *(const bf16x2*)(QKVG + r * 4096 + h * 128 + lane * 2);
  float2 k2 = *(const float2*)(ksum + (b * 8 + h) * 128 + lane * 2);
  float p = (float)q2[0] * k2.x + (float)q2[1] * k2.y;
#pragma unroll
  for (int o = 32; o > 0; o >>= 1) p += __shfl_xor(p, o, 64);
  if (lane == 0) den[((long)(b * 8 + h)) * 4096 + s] = p * kScale + 4096.0f;
}

// ---------------------------------------------------------------------------
extern "C" void kernel_launch(void* const* d_in, const int* in_sizes, int n_in,
                              void* d_out, int out_size, void* d_ws, size_t ws_size,
                              hipStream_t stream)
{
  const float* X      = (const float*)d_in[0];
  const float* Wq     = (const float*)d_in[1];
  const float* Wk     = (const float*)d_in[2];
  const float* Wv     = (const float*)d_in[3];
  const float* Wg     = (const float*)d_in[4];
  const float* Wo     = (const float*)d_in[5];
  const float* lepe_w = (const float*)d_in[6];
  const float* lepe_b = (const float*)d_in[7];
  float* out = (float*)d_out;

  char* ws = (char*)d_ws;
  bf16*   Xb    = (bf16*)(ws);
  float*  kvp   = (float*)(ws);
  float*  ksump = (float*)(ws + 16777216);
  float*  vsump = (float*)(ws + 16908288);
  bf16*   Wcat  = (bf16*)(ws + 33554432);
  bf16*   Wob   = (bf16*)(ws + 41943040);
  float2* tab   = (float2*)(ws + 44040192);
  bf16*   QKVG  = (bf16*)(ws + 46137344);
  float*  ksum  = (float*)(ws + 180355072);
  float*  vsum  = (float*)(ws + 180371456);
  bf16*   kvT   = (bf16*)(ws + 180387840);
  float*  den   = (float*)(ws + 181436416);
  bf16*   obuf  = (bf16*)(ws + 181960704);

  prep_kernel<<<22528, 256, 0, stream>>>(X, Wq, Wk, Wv, Wg, Wo, Xb, Wcat, Wob, tab);

  gemm_qkvg<<<dim3(128, 32), 256, 0, stream>>>(Xb, Wcat, QKVG, tab);

  kv_mfma<<<dim3(8, 32), 256, 0, stream>>>(QKVG, kvp, ksump, vsump);
  kv_reduce<<<2048, 256, 0, stream>>>(kvp, ksump, vsump, kvT, ksum, vsum);
  den_kernel<<<32768, 256, 0, stream>>>(QKVG, ksum, den);

  gemm_num<<<dim3(32, 8, 4), 256, 0, stream>>>(QKVG, kvT, den, vsum, lepe_w, lepe_b, obuf);

  gemm_final<<<dim3(128, 8), 256, 0, stream>>>(obuf, Wob, out);
}

// Round 5
// 449.357 us; speedup vs baseline: 1.3873x; 1.1663x over previous
//
#include <hip/hip_runtime.h>
#include <math.h>
#include <stdint.h>

// ---------------------------------------------------------------------------
// MalaAttention on MI355X (gfx950). Round 5:
//  - XCD-aware block swizzle on proj/final GEMMs (L2 reuse; FETCH 196->~100MB)
//  - uniform coalesced C-store via LDS tile (256B/row) in proj GEMM
//  - den computed inside gemm_num's K-loop (den_kernel removed)
//
// Workspace layout (bytes):
//   Xb    @ 0          32MB  bf16 X        (dead after proj -> kvp/ksump/vsump)
//   kvp   @ 0          16MB  f32 [8][bh][128][128] kv partials
//   ksump @ 16777216  128KB  f32 [8][bh][128]
//   vsump @ 16908288  128KB  f32 [8][bh][128]
//   Wcat  @ 33554432    8MB  bf16 [Wq;Wk;Wv;Wg]
//   Wob   @ 41943040    2MB  bf16 Wo
//   tab   @ 44040192    2MB  float2 [4096][64] rope sin/cos
//   QKVG  @ 46137344  128MB  bf16 [16384][4096] col blocks: q|k|v|g
//   ksum  @ 180355072  16KB  f32 [bh][128]
//   vsum  @ 180371456  16KB  f32 [bh][128]
//   kvT   @ 180387840   1MB  bf16 kvT[bh][e][d]
//   obuf  @ 181960704  32MB  bf16 gated out
// ---------------------------------------------------------------------------

typedef __bf16 bf16;
typedef __bf16 bf16x2 __attribute__((ext_vector_type(2)));
typedef __bf16 bf16x4 __attribute__((ext_vector_type(4)));
typedef __bf16 bf16x8 __attribute__((ext_vector_type(8)));
typedef float f32x4 __attribute__((ext_vector_type(4)));

static constexpr float kScale = 0.08838834764831845f; // 1/sqrt(128)

__device__ __forceinline__ void async_copy16(const void* g, void* l) {
  __builtin_amdgcn_global_load_lds(
      (const __attribute__((address_space(1))) void*)(uintptr_t)g,
      (__attribute__((address_space(3))) void*)(uintptr_t)l, 16, 0, 0);
}

// ---------------------------------------------------------------------------
// Proj GEMM: QKVG = Xb @ Wcat^T, RoPE fused in-epilogue for q,k (by<16).
// 1D grid 4096, XCD-swizzled: xcd=bid&7 -> x-stripe of 16, sweep y.
// ---------------------------------------------------------------------------
__global__ __launch_bounds__(256, 2) void gemm_qkvg(
    const bf16* __restrict__ A, const bf16* __restrict__ Bw,
    bf16* __restrict__ C, const float2* __restrict__ tab)
{
  __shared__ __align__(16) char smem[34816];   // max(As+Bs=16K, T=128*136*2)
  bf16* As = (bf16*)smem;
  bf16* Bs = (bf16*)(smem + 8192);
  bf16* T  = (bf16*)smem;                      // epilogue tile, stride 136

  const int t = threadIdx.x;
  const int bid = blockIdx.x;
  const int xcd = bid & 7, n = bid >> 3;
  const int bx = xcd * 16 + (n & 15);          // 0..127 (m tile)
  const int by = n >> 4;                       // 0..31  (n tile)
  const long m0 = (long)bx * 128;
  A  += m0 * 1024;
  Bw += (long)by * 131072;
  C  += m0 * 4096 + (long)by * 128;

  const int i0 = t, i1 = t + 256;
  const bf16* gA0 = A  + (long)(i0 >> 2) * 1024 + (i0 & 3) * 8;
  const bf16* gA1 = A  + (long)(i1 >> 2) * 1024 + (i1 & 3) * 8;
  const bf16* gB0 = Bw + (long)(i0 >> 2) * 1024 + (i0 & 3) * 8;
  const bf16* gB1 = Bw + (long)(i1 >> 2) * 1024 + (i1 & 3) * 8;
  bf16* lA0 = As + i0 * 8; bf16* lA1 = As + i1 * 8;
  bf16* lB0 = Bs + i0 * 8; bf16* lB1 = Bs + i1 * 8;

  const int lane = t & 63, wv = t >> 6;
  const int moff = (wv & 1) * 64, noff = (wv >> 1) * 64;
  const int fm = lane & 15, fq = lane >> 4;

  f32x4 acc[4][4] = {};

  for (int k0 = 0; k0 < 1024; k0 += 32) {
    async_copy16(gA0, lA0); async_copy16(gA1, lA1);
    async_copy16(gB0, lB0); async_copy16(gB1, lB1);
    gA0 += 32; gA1 += 32; gB0 += 32; gB1 += 32;
    __syncthreads();
    bf16x8 af[4], bfv[4];
#pragma unroll
    for (int i = 0; i < 4; ++i) {
      af[i]  = *(const bf16x8*)(As + (moff + i * 16 + fm) * 32 + fq * 8);
      bfv[i] = *(const bf16x8*)(Bs + (noff + i * 16 + fm) * 32 + fq * 8);
    }
#pragma unroll
    for (int i = 0; i < 4; ++i)
#pragma unroll
      for (int j = 0; j < 4; ++j)
        acc[i][j] = __builtin_amdgcn_mfma_f32_16x16x32_bf16(af[i], bfv[j], acc[i][j], 0, 0, 0);
    __syncthreads();
  }

  // acc -> LDS tile (all tiles; uniform coalesced store path)
#pragma unroll
  for (int i = 0; i < 4; ++i)
#pragma unroll
    for (int j = 0; j < 4; ++j)
#pragma unroll
      for (int r = 0; r < 4; ++r)
        T[(moff + i * 16 + fq * 4 + r) * 136 + noff + j * 16 + fm] = (bf16)acc[i][j][r];
  __syncthreads();

  if (by < 16) {  // RoPE pair rotation in LDS
#pragma unroll
    for (int it = 0; it < 32; ++it) {
      const int pi = t + it * 256;
      const int row = pi >> 6, i = pi & 63;
      const int s = (int)((m0 + row) & 4095);
      const float2 sc = tab[s * 64 + i];
      float x1 = (float)T[row * 136 + i];
      float x2 = (float)T[row * 136 + i + 64];
      T[row * 136 + i]      = (bf16)(x1 * sc.y - x2 * sc.x);
      T[row * 136 + i + 64] = (bf16)(x2 * sc.y + x1 * sc.x);
    }
    __syncthreads();
  }

  // coalesced store: 16 lanes x bf16x8 = 256B per row (full lines)
  const int srow0 = t >> 4, sc0 = (t & 15) * 8;
#pragma unroll
  for (int it = 0; it < 8; ++it) {
    const int row = it * 16 + srow0;
    *(bf16x8*)(C + (long)row * 4096 + sc0) = *(const bf16x8*)(T + row * 136 + sc0);
  }
}

// ---------------------------------------------------------------------------
// Final NT GEMM: out = obuf @ Wo^T, fp32 out. 1D grid 1024, XCD-swizzled.
// ---------------------------------------------------------------------------
__global__ __launch_bounds__(256, 2) void gemm_final(
    const bf16* __restrict__ A, const bf16* __restrict__ Bw,
    float* __restrict__ C)
{
  __shared__ __align__(16) bf16 As[128 * 32];
  __shared__ __align__(16) bf16 Bs[128 * 32];
  const int t = threadIdx.x;
  const int bid = blockIdx.x;
  const int xcd = bid & 7, n = bid >> 3;
  const int bx = xcd * 16 + (n & 15);          // 0..127
  const int by = n >> 4;                       // 0..7
  const long m0 = (long)bx * 128;
  A  += m0 * 1024;
  Bw += (long)by * 131072;
  C  += m0 * 1024 + (long)by * 128;

  const int i0 = t, i1 = t + 256;
  const bf16* gA0 = A  + (long)(i0 >> 2) * 1024 + (i0 & 3) * 8;
  const bf16* gA1 = A  + (long)(i1 >> 2) * 1024 + (i1 & 3) * 8;
  const bf16* gB0 = Bw + (long)(i0 >> 2) * 1024 + (i0 & 3) * 8;
  const bf16* gB1 = Bw + (long)(i1 >> 2) * 1024 + (i1 & 3) * 8;
  bf16* lA0 = As + i0 * 8; bf16* lA1 = As + i1 * 8;
  bf16* lB0 = Bs + i0 * 8; bf16* lB1 = Bs + i1 * 8;

  const int lane = t & 63, wv = t >> 6;
  const int moff = (wv & 1) * 64, noff = (wv >> 1) * 64;
  const int fm = lane & 15, fq = lane >> 4;

  f32x4 acc[4][4] = {};

  for (int k0 = 0; k0 < 1024; k0 += 32) {
    async_copy16(gA0, lA0); async_copy16(gA1, lA1);
    async_copy16(gB0, lB0); async_copy16(gB1, lB1);
    gA0 += 32; gA1 += 32; gB0 += 32; gB1 += 32;
    __syncthreads();
    bf16x8 af[4], bfv[4];
#pragma unroll
    for (int i = 0; i < 4; ++i) {
      af[i]  = *(const bf16x8*)(As + (moff + i * 16 + fm) * 32 + fq * 8);
      bfv[i] = *(const bf16x8*)(Bs + (noff + i * 16 + fm) * 32 + fq * 8);
    }
#pragma unroll
    for (int i = 0; i < 4; ++i)
#pragma unroll
      for (int j = 0; j < 4; ++j)
        acc[i][j] = __builtin_amdgcn_mfma_f32_16x16x32_bf16(af[i], bfv[j], acc[i][j], 0, 0, 0);
    __syncthreads();
  }

#pragma unroll
  for (int i = 0; i < 4; ++i)
#pragma unroll
    for (int j = 0; j < 4; ++j)
#pragma unroll
      for (int r = 0; r < 4; ++r)
        C[(long)(moff + i * 16 + fq * 4 + r) * 1024 + noff + j * 16 + fm] = acc[i][j][r];
}

// ---------------------------------------------------------------------------
// num GEMM (per b,h: M=4096 N=128 K=128) + fused den + mala/LePE/gate epilogue.
// den accumulated in-loop from staged As (roped q) x LDS ksum.
// ---------------------------------------------------------------------------
__global__ __launch_bounds__(256, 2) void gemm_num(
    const bf16* __restrict__ QKVG, const bf16* __restrict__ kvTall,
    const float* __restrict__ ksum, const float* __restrict__ vsum,
    const float* __restrict__ lepe_w, const float* __restrict__ lepe_b,
    bf16* __restrict__ obuf)
{
  __shared__ __align__(16) char smem[34816];
  bf16* As = (bf16*)smem;
  bf16* Bs = (bf16*)(smem + 8192);
  bf16* T  = (bf16*)smem;                      // epilogue, stride 136
  __shared__ float sden[128], svsum[128], slb[128], sksum[128];
  __shared__ float slw[5][128];

  const int t = threadIdx.x;
  const int h = blockIdx.y, b = blockIdx.z;
  const int bh = b * 8 + h;
  const long m0 = (long)blockIdx.x * 128;
  const bf16* A  = QKVG + (long)b * 16777216 + m0 * 4096 + h * 128;
  const bf16* Bw = kvTall + (long)bh * 16384;

  if (t < 128) {
    sksum[t] = ksum[bh * 128 + t];
    svsum[t] = vsum[bh * 128 + t];
    slb[t]   = lepe_b[h * 128 + t];
#pragma unroll
    for (int j = 0; j < 5; ++j) slw[j][t] = lepe_w[(h * 128 + t) * 5 + j];
  }

  const int i0 = t, i1 = t + 256;
  const bf16* gA0 = A + (long)(i0 >> 2) * 4096 + (i0 & 3) * 8;
  const bf16* gA1 = A + (long)(i1 >> 2) * 4096 + (i1 & 3) * 8;
  const bf16* gB0 = Bw + (long)(i0 >> 2) * 128 + (i0 & 3) * 8;
  const bf16* gB1 = Bw + (long)(i1 >> 2) * 128 + (i1 & 3) * 8;
  bf16* lA0 = As + i0 * 8; bf16* lA1 = As + i1 * 8;
  bf16* lB0 = Bs + i0 * 8; bf16* lB1 = Bs + i1 * 8;

  const int lane = t & 63, wv = t >> 6;
  const int moff = (wv & 1) * 64, noff = (wv >> 1) * 64;
  const int fm = lane & 15, fq = lane >> 4;

  f32x4 acc[4][4] = {};
  float dacc = 0.f;

  for (int k0 = 0; k0 < 128; k0 += 32) {
    async_copy16(gA0, lA0); async_copy16(gA1, lA1);
    async_copy16(gB0, lB0); async_copy16(gB1, lB1);
    gA0 += 32; gA1 += 32; gB0 += 32; gB1 += 32;
    __syncthreads();
    bf16x8 af[4], bfv[4];
#pragma unroll
    for (int i = 0; i < 4; ++i) {
      af[i]  = *(const bf16x8*)(As + (moff + i * 16 + fm) * 32 + fq * 8);
      bfv[i] = *(const bf16x8*)(Bs + (noff + i * 16 + fm) * 32 + fq * 8);
    }
#pragma unroll
    for (int i = 0; i < 4; ++i)
#pragma unroll
      for (int j = 0; j < 4; ++j)
        acc[i][j] = __builtin_amdgcn_mfma_f32_16x16x32_bf16(af[i], bfv[j], acc[i][j], 0, 0, 0);
    if (t < 128) {                 // den partial: row t, k-chunk k0..k0+32
#pragma unroll
      for (int c8 = 0; c8 < 4; ++c8) {
        bf16x8 q8 = *(const bf16x8*)(As + t * 32 + c8 * 8);
#pragma unroll
        for (int e = 0; e < 8; ++e) dacc += (float)q8[e] * sksum[k0 + c8 * 8 + e];
      }
    }
    __syncthreads();
  }
  if (t < 128) sden[t] = dacc * kScale + 4096.0f;

  // attn -> LDS tile (needs sden: barrier below covers both T and sden)
#pragma unroll
  for (int i = 0; i < 4; ++i)
#pragma unroll
    for (int j = 0; j < 4; ++j)
#pragma unroll
      for (int r = 0; r < 4; ++r) {
        const int row = moff + i * 16 + fq * 4 + r;
        const int col = noff + j * 16 + fm;
        T[row * 136 + col] = (bf16)(acc[i][j][r] * kScale + svsum[col]);
      }
  __syncthreads();

  // row phase: coalesced. lane covers cols [lane*2, lane*2+1].
  const int c2 = lane * 2;
  const float w0[5] = {slw[0][c2], slw[1][c2], slw[2][c2], slw[3][c2], slw[4][c2]};
  const float w1[5] = {slw[0][c2+1], slw[1][c2+1], slw[2][c2+1], slw[3][c2+1], slw[4][c2+1]};
  const float lb0 = slb[c2], lb1 = slb[c2 + 1];
  for (int rr = 0; rr < 32; ++rr) {
    const int row = wv * 32 + rr;
    const int s = (int)(m0 + row);
    const long grow = (long)b * 4096 + s;
    const float rden = 1.0f / sden[row];
    const bf16* vrow = QKVG + grow * 4096 + 2048 + h * 128 + c2;
    bf16x2 a2 = *(const bf16x2*)(T + row * 136 + c2);
    float lep0 = lb0, lep1 = lb1;
#pragma unroll
    for (int jt = 0; jt < 5; ++jt) {
      const int srow = s + jt - 2;
      if (srow >= 0 && srow < 4096) {                 // wave-uniform branch
        bf16x2 v2 = *(const bf16x2*)(vrow + (long)(jt - 2) * 4096);
        lep0 += (float)v2[0] * w0[jt];
        lep1 += (float)v2[1] * w1[jt];
      }
    }
    bf16x2 g2 = *(const bf16x2*)(QKVG + grow * 4096 + 3072 + h * 128 + c2);
    bf16x2 o2;
    o2[0] = (bf16)(((float)a2[0] * rden + lep0) * (float)g2[0]);
    o2[1] = (bf16)(((float)a2[1] * rden + lep1) * (float)g2[1]);
    *(bf16x2*)(obuf + grow * 1024 + h * 128 + c2) = o2;
  }
}

// ---------------------------------------------------------------------------
// prep: cast X->bf16, cast/concat weights, build rope sin/cos table.
// ---------------------------------------------------------------------------
__global__ void prep_kernel(const float* __restrict__ X, const float* __restrict__ Wq,
                            const float* __restrict__ Wk, const float* __restrict__ Wv,
                            const float* __restrict__ Wg, const float* __restrict__ Wo,
                            bf16* __restrict__ Xb, bf16* __restrict__ Wcat,
                            bf16* __restrict__ Wob, float2* __restrict__ tab)
{
  const int blk = blockIdx.x;
  if (blk < 16384) {
    long g = ((long)blk * 256 + threadIdx.x) * 4;
    float4 v = *(const float4*)(X + g);
    bf16x4 o = {(bf16)v.x, (bf16)v.y, (bf16)v.z, (bf16)v.w};
    *(bf16x4*)(Xb + g) = o;
  } else if (blk < 21504) {
    long g = ((long)(blk - 16384) * 256 + threadIdx.x) * 4;
    if (g < 4194304) {
      long idx = g & 1048575;
      int sel = (int)(g >> 20);
      const float* s = sel == 0 ? Wq : sel == 1 ? Wk : sel == 2 ? Wv : Wg;
      float4 v = *(const float4*)(s + idx);
      bf16x4 o = {(bf16)v.x, (bf16)v.y, (bf16)v.z, (bf16)v.w};
      *(bf16x4*)(Wcat + g) = o;
    } else {
      long idx = g - 4194304;
      float4 v = *(const float4*)(Wo + idx);
      bf16x4 o = {(bf16)v.x, (bf16)v.y, (bf16)v.z, (bf16)v.w};
      *(bf16x4*)(Wob + idx) = o;
    }
  } else {
    int idx = (blk - 21504) * 256 + threadIdx.x;
    int s = idx >> 6, i = idx & 63;
    float inv = powf(10000.0f, -((float)(2 * i)) / 128.0f);
    float ang = (float)s * inv;
    float sn, cs;
    sincosf(ang, &sn, &cs);
    tab[idx] = make_float2(sn, cs);
  }
}

// ---------------------------------------------------------------------------
// kv via MFMA with in-LDS transpose. Grid (8, 32). No atomics.
// ---------------------------------------------------------------------------
__global__ __launch_bounds__(256, 2) void kv_mfma(
    const bf16* __restrict__ QKVG, float* __restrict__ kvp,
    float* __restrict__ ksump, float* __restrict__ vsump)
{
  __shared__ __align__(16) bf16 VT[128 * 40];
  __shared__ __align__(16) bf16 KT[128 * 40];
  const int t = threadIdx.x;
  const int chunk = blockIdx.x, bh = blockIdx.y;
  const int b = bh >> 3, h = bh & 7;
  const long rowbase = ((long)b * 4096 + chunk * 512) * 4096 + h * 128;
  const bf16* Kg = QKVG + rowbase + 1024;
  const bf16* Vg = QKVG + rowbase + 2048;

  const int sp = t >> 4, fc = t & 15;
  const int lane = t & 63, wv = t >> 6;
  const int eoff = (wv & 1) * 64, doff = (wv >> 1) * 64;
  const int fm = lane & 15, fq = lane >> 4;
  const int srow = t & 127;
  const bool sumK = t >= 128;

  f32x4 acc[4][4] = {};
  float rsum = 0.f;

  for (int sb = 0; sb < 512; sb += 32) {
    const long go = (long)(sb + 2 * sp) * 4096 + fc * 8;
    bf16x8 v0 = *(const bf16x8*)(Vg + go);
    bf16x8 v1 = *(const bf16x8*)(Vg + go + 4096);
    bf16x8 k0 = *(const bf16x8*)(Kg + go);
    bf16x8 k1 = *(const bf16x8*)(Kg + go + 4096);
#pragma unroll
    for (int j = 0; j < 8; ++j) {
      const int f = fc * 8 + j;
      bf16x2 vp2 = {v0[j], v1[j]};
      bf16x2 kp2 = {k0[j], k1[j]};
      *(bf16x2*)(VT + f * 40 + 2 * sp) = vp2;
      *(bf16x2*)(KT + f * 40 + 2 * sp) = kp2;
    }
    __syncthreads();
    bf16x8 af[4], bfv[4];
#pragma unroll
    for (int i = 0; i < 4; ++i) {
      af[i]  = *(const bf16x8*)(VT + (eoff + i * 16 + fm) * 40 + fq * 8);
      bfv[i] = *(const bf16x8*)(KT + (doff + i * 16 + fm) * 40 + fq * 8);
    }
#pragma unroll
    for (int i = 0; i < 4; ++i)
#pragma unroll
      for (int j = 0; j < 4; ++j)
        acc[i][j] = __builtin_amdgcn_mfma_f32_16x16x32_bf16(af[i], bfv[j], acc[i][j], 0, 0, 0);
    const bf16* rp = (sumK ? KT : VT) + srow * 40;
#pragma unroll
    for (int i = 0; i < 4; ++i) {
      bf16x8 r8 = *(const bf16x8*)(rp + i * 8);
#pragma unroll
      for (int j = 0; j < 8; ++j) rsum += (float)r8[j];
    }
    __syncthreads();
  }

  float* plane = kvp + ((long)chunk * 32 + bh) * 16384;
#pragma unroll
  for (int i = 0; i < 4; ++i)
#pragma unroll
    for (int j = 0; j < 4; ++j)
#pragma unroll
      for (int r = 0; r < 4; ++r)
        plane[(long)(eoff + i * 16 + fq * 4 + r) * 128 + (doff + j * 16 + fm)] = acc[i][j][r];
  float* sdst = (sumK ? ksump : vsump) + ((long)chunk * 32 + bh) * 128 + srow;
  *sdst = rsum;
}

// Fold 8 chunk partials -> bf16 kvT + f32 ksum/vsum.
__global__ void kv_reduce(const float* __restrict__ kvp, const float* __restrict__ ksump,
                          const float* __restrict__ vsump, bf16* __restrict__ kvT,
                          float* __restrict__ ksum, float* __restrict__ vsum)
{
  long g = (long)blockIdx.x * 256 + threadIdx.x;
  long bh = g >> 14, idx = g & 16383;
  float s = 0.f;
#pragma unroll
  for (int c = 0; c < 8; ++c) s += kvp[((long)c * 32 + bh) * 16384 + idx];
  kvT[g] = (bf16)s;
  if (g < 8192) {
    int bh2 = (int)(g >> 8), rem = (int)(g & 255), f = rem & 127;
    const float* src = (rem >> 7) ? ksump : vsump;
    float* dst = (rem >> 7) ? ksum : vsum;
    float s2 = 0.f;
#pragma unroll
    for (int c = 0; c < 8; ++c) s2 += src[((long)c * 32 + bh2) * 128 + f];
    dst[bh2 * 128 + f] = s2;
  }
}

// ---------------------------------------------------------------------------
extern "C" void kernel_launch(void* const* d_in, const int* in_sizes, int n_in,
                              void* d_out, int out_size, void* d_ws, size_t ws_size,
                              hipStream_t stream)
{
  const float* X      = (const float*)d_in[0];
  const float* Wq     = (const float*)d_in[1];
  const float* Wk     = (const float*)d_in[2];
  const float* Wv     = (const float*)d_in[3];
  const float* Wg     = (const float*)d_in[4];
  const float* Wo     = (const float*)d_in[5];
  const float* lepe_w = (const float*)d_in[6];
  const float* lepe_b = (const float*)d_in[7];
  float* out = (float*)d_out;

  char* ws = (char*)d_ws;
  bf16*   Xb    = (bf16*)(ws);
  float*  kvp   = (float*)(ws);
  float*  ksump = (float*)(ws + 16777216);
  float*  vsump = (float*)(ws + 16908288);
  bf16*   Wcat  = (bf16*)(ws + 33554432);
  bf16*   Wob   = (bf16*)(ws + 41943040);
  float2* tab   = (float2*)(ws + 44040192);
  bf16*   QKVG  = (bf16*)(ws + 46137344);
  float*  ksum  = (float*)(ws + 180355072);
  float*  vsum  = (float*)(ws + 180371456);
  bf16*   kvT   = (bf16*)(ws + 180387840);
  bf16*   obuf  = (bf16*)(ws + 181960704);

  prep_kernel<<<22528, 256, 0, stream>>>(X, Wq, Wk, Wv, Wg, Wo, Xb, Wcat, Wob, tab);

  gemm_qkvg<<<4096, 256, 0, stream>>>(Xb, Wcat, QKVG, tab);

  kv_mfma<<<dim3(8, 32), 256, 0, stream>>>(QKVG, kvp, ksump, vsump);
  kv_reduce<<<2048, 256, 0, stream>>>(kvp, ksump, vsump, kvT, ksum, vsum);

  gemm_num<<<dim3(32, 8, 4), 256, 0, stream>>>(QKVG, kvT, ksum, vsum, lepe_w, lepe_b, obuf);

  gemm_final<<<1024, 256, 0, stream>>>(obuf, Wob, out);
}

// Round 6
// 445.997 us; speedup vs baseline: 1.3977x; 1.0075x over previous
//
#include <hip/hip_runtime.h>
#include <math.h>
#include <stdint.h>

// ---------------------------------------------------------------------------
// MalaAttention on MI355X (gfx950). Round 6:
//  - half-tile epilogues in gemm_qkvg/gemm_num: LDS 34.8K->17.4K per block,
//    doubling occupancy (42% was LDS-capped; K-loop needs only 16KB)
//  - kv split-S 8->16 chunks (512 blocks, 2/CU); ksump/vsump in dead tab slot
//
// Workspace layout (bytes):
//   Xb    @ 0          32MB  bf16 X        (dead after proj -> kvp)
//   kvp   @ 0          32MB  f32 [16][bh][128][128] kv partials
//   Wcat  @ 33554432    8MB  bf16 [Wq;Wk;Wv;Wg]
//   Wob   @ 41943040    2MB  bf16 Wo
//   tab   @ 44040192    2MB  float2 [4096][64] rope sin/cos (dead after proj)
//   ksump @ 44040192  256KB  f32 [16][bh][128]   (aliases tab)
//   vsump @ 44302336  256KB  f32 [16][bh][128]
//   QKVG  @ 46137344  128MB  bf16 [16384][4096] col blocks: q|k|v|g
//   ksum  @ 180355072  16KB  f32 [bh][128]
//   vsum  @ 180371456  16KB  f32 [bh][128]
//   kvT   @ 180387840   1MB  bf16 kvT[bh][e][d]
//   obuf  @ 181960704  32MB  bf16 gated out
// ---------------------------------------------------------------------------

typedef __bf16 bf16;
typedef __bf16 bf16x2 __attribute__((ext_vector_type(2)));
typedef __bf16 bf16x4 __attribute__((ext_vector_type(4)));
typedef __bf16 bf16x8 __attribute__((ext_vector_type(8)));
typedef float f32x4 __attribute__((ext_vector_type(4)));

static constexpr float kScale = 0.08838834764831845f; // 1/sqrt(128)

__device__ __forceinline__ void async_copy16(const void* g, void* l) {
  __builtin_amdgcn_global_load_lds(
      (const __attribute__((address_space(1))) void*)(uintptr_t)g,
      (__attribute__((address_space(3))) void*)(uintptr_t)l, 16, 0, 0);
}

// ---------------------------------------------------------------------------
// Proj GEMM: QKVG = Xb @ Wcat^T, RoPE fused in-epilogue for q,k (by<16).
// 1D grid 4096, XCD-swizzled. Epilogue in two 64-row half-tiles (LDS 17.4K).
// ---------------------------------------------------------------------------
__global__ __launch_bounds__(256, 2) void gemm_qkvg(
    const bf16* __restrict__ A, const bf16* __restrict__ Bw,
    bf16* __restrict__ C, const float2* __restrict__ tab)
{
  __shared__ __align__(16) char smem[17408];   // K-loop 16K | T = 64x136 bf16
  bf16* As = (bf16*)smem;
  bf16* Bs = (bf16*)(smem + 8192);
  bf16* T  = (bf16*)smem;

  const int t = threadIdx.x;
  const int bid = blockIdx.x;
  const int xcd = bid & 7, n = bid >> 3;
  const int bx = xcd * 16 + (n & 15);          // 0..127 (m tile)
  const int by = n >> 4;                       // 0..31  (n tile)
  const long m0 = (long)bx * 128;
  A  += m0 * 1024;
  Bw += (long)by * 131072;
  C  += m0 * 4096 + (long)by * 128;

  const int i0 = t, i1 = t + 256;
  const bf16* gA0 = A  + (long)(i0 >> 2) * 1024 + (i0 & 3) * 8;
  const bf16* gA1 = A  + (long)(i1 >> 2) * 1024 + (i1 & 3) * 8;
  const bf16* gB0 = Bw + (long)(i0 >> 2) * 1024 + (i0 & 3) * 8;
  const bf16* gB1 = Bw + (long)(i1 >> 2) * 1024 + (i1 & 3) * 8;
  bf16* lA0 = As + i0 * 8; bf16* lA1 = As + i1 * 8;
  bf16* lB0 = Bs + i0 * 8; bf16* lB1 = Bs + i1 * 8;

  const int lane = t & 63, wv = t >> 6;
  const int moff = (wv & 1) * 64, noff = (wv >> 1) * 64;
  const int fm = lane & 15, fq = lane >> 4;

  f32x4 acc[4][4] = {};

  for (int k0 = 0; k0 < 1024; k0 += 32) {
    async_copy16(gA0, lA0); async_copy16(gA1, lA1);
    async_copy16(gB0, lB0); async_copy16(gB1, lB1);
    gA0 += 32; gA1 += 32; gB0 += 32; gB1 += 32;
    __syncthreads();
    bf16x8 af[4], bfv[4];
#pragma unroll
    for (int i = 0; i < 4; ++i) {
      af[i]  = *(const bf16x8*)(As + (moff + i * 16 + fm) * 32 + fq * 8);
      bfv[i] = *(const bf16x8*)(Bs + (noff + i * 16 + fm) * 32 + fq * 8);
    }
#pragma unroll
    for (int i = 0; i < 4; ++i)
#pragma unroll
      for (int j = 0; j < 4; ++j)
        acc[i][j] = __builtin_amdgcn_mfma_f32_16x16x32_bf16(af[i], bfv[j], acc[i][j], 0, 0, 0);
    __syncthreads();
  }

  // epilogue: two 64-row half-tiles through T (stride 136)
#pragma unroll
  for (int half = 0; half < 2; ++half) {
    if ((wv & 1) == half) {      // waves whose moff == half*64
#pragma unroll
      for (int i = 0; i < 4; ++i)
#pragma unroll
        for (int j = 0; j < 4; ++j)
#pragma unroll
          for (int r = 0; r < 4; ++r)
            T[(i * 16 + fq * 4 + r) * 136 + noff + j * 16 + fm] = (bf16)acc[i][j][r];
    }
    __syncthreads();
    if (by < 16) {  // RoPE pair rotation in LDS
#pragma unroll
      for (int it = 0; it < 16; ++it) {
        const int pi = t + it * 256;       // 4096 pairs
        const int row = pi >> 6, i = pi & 63;
        const int s = (int)((m0 + half * 64 + row) & 4095);
        const float2 sc = tab[s * 64 + i];
        float x1 = (float)T[row * 136 + i];
        float x2 = (float)T[row * 136 + i + 64];
        T[row * 136 + i]      = (bf16)(x1 * sc.y - x2 * sc.x);
        T[row * 136 + i + 64] = (bf16)(x2 * sc.y + x1 * sc.x);
      }
      __syncthreads();
    }
    // coalesced store: 16 lanes x bf16x8 = 256B per row
    const int srow0 = t >> 4, sc0 = (t & 15) * 8;
#pragma unroll
    for (int it = 0; it < 4; ++it) {
      const int row = it * 16 + srow0;
      *(bf16x8*)(C + (long)(half * 64 + row) * 4096 + sc0) = *(const bf16x8*)(T + row * 136 + sc0);
    }
    __syncthreads();  // T reads done before next half overwrites
  }
}

// ---------------------------------------------------------------------------
// Final NT GEMM: out = obuf @ Wo^T, fp32 out. 1D grid 1024, XCD-swizzled.
// ---------------------------------------------------------------------------
__global__ __launch_bounds__(256, 2) void gemm_final(
    const bf16* __restrict__ A, const bf16* __restrict__ Bw,
    float* __restrict__ C)
{
  __shared__ __align__(16) bf16 As[128 * 32];
  __shared__ __align__(16) bf16 Bs[128 * 32];
  const int t = threadIdx.x;
  const int bid = blockIdx.x;
  const int xcd = bid & 7, n = bid >> 3;
  const int bx = xcd * 16 + (n & 15);
  const int by = n >> 4;
  const long m0 = (long)bx * 128;
  A  += m0 * 1024;
  Bw += (long)by * 131072;
  C  += m0 * 1024 + (long)by * 128;

  const int i0 = t, i1 = t + 256;
  const bf16* gA0 = A  + (long)(i0 >> 2) * 1024 + (i0 & 3) * 8;
  const bf16* gA1 = A  + (long)(i1 >> 2) * 1024 + (i1 & 3) * 8;
  const bf16* gB0 = Bw + (long)(i0 >> 2) * 1024 + (i0 & 3) * 8;
  const bf16* gB1 = Bw + (long)(i1 >> 2) * 1024 + (i1 & 3) * 8;
  bf16* lA0 = As + i0 * 8; bf16* lA1 = As + i1 * 8;
  bf16* lB0 = Bs + i0 * 8; bf16* lB1 = Bs + i1 * 8;

  const int lane = t & 63, wv = t >> 6;
  const int moff = (wv & 1) * 64, noff = (wv >> 1) * 64;
  const int fm = lane & 15, fq = lane >> 4;

  f32x4 acc[4][4] = {};

  for (int k0 = 0; k0 < 1024; k0 += 32) {
    async_copy16(gA0, lA0); async_copy16(gA1, lA1);
    async_copy16(gB0, lB0); async_copy16(gB1, lB1);
    gA0 += 32; gA1 += 32; gB0 += 32; gB1 += 32;
    __syncthreads();
    bf16x8 af[4], bfv[4];
#pragma unroll
    for (int i = 0; i < 4; ++i) {
      af[i]  = *(const bf16x8*)(As + (moff + i * 16 + fm) * 32 + fq * 8);
      bfv[i] = *(const bf16x8*)(Bs + (noff + i * 16 + fm) * 32 + fq * 8);
    }
#pragma unroll
    for (int i = 0; i < 4; ++i)
#pragma unroll
      for (int j = 0; j < 4; ++j)
        acc[i][j] = __builtin_amdgcn_mfma_f32_16x16x32_bf16(af[i], bfv[j], acc[i][j], 0, 0, 0);
    __syncthreads();
  }

#pragma unroll
  for (int i = 0; i < 4; ++i)
#pragma unroll
    for (int j = 0; j < 4; ++j)
#pragma unroll
      for (int r = 0; r < 4; ++r)
        C[(long)(moff + i * 16 + fq * 4 + r) * 1024 + noff + j * 16 + fm] = acc[i][j][r];
}

// ---------------------------------------------------------------------------
// num GEMM (per b,h: M=4096 N=128 K=128) + fused den + mala/LePE/gate.
// Half-tile epilogue (T = 64x136) for occupancy.
// ---------------------------------------------------------------------------
__global__ __launch_bounds__(256, 2) void gemm_num(
    const bf16* __restrict__ QKVG, const bf16* __restrict__ kvTall,
    const float* __restrict__ ksum, const float* __restrict__ vsum,
    const float* __restrict__ lepe_w, const float* __restrict__ lepe_b,
    bf16* __restrict__ obuf)
{
  __shared__ __align__(16) char smem[17408];
  bf16* As = (bf16*)smem;
  bf16* Bs = (bf16*)(smem + 8192);
  bf16* T  = (bf16*)smem;                      // epilogue, 64 rows, stride 136
  __shared__ float sden[128], svsum[128], slb[128], sksum[128];
  __shared__ float slw[5][128];

  const int t = threadIdx.x;
  const int h = blockIdx.y, b = blockIdx.z;
  const int bh = b * 8 + h;
  const long m0 = (long)blockIdx.x * 128;
  const bf16* A  = QKVG + (long)b * 16777216 + m0 * 4096 + h * 128;
  const bf16* Bw = kvTall + (long)bh * 16384;

  if (t < 128) {
    sksum[t] = ksum[bh * 128 + t];
    svsum[t] = vsum[bh * 128 + t];
    slb[t]   = lepe_b[h * 128 + t];
#pragma unroll
    for (int j = 0; j < 5; ++j) slw[j][t] = lepe_w[(h * 128 + t) * 5 + j];
  }

  const int i0 = t, i1 = t + 256;
  const bf16* gA0 = A + (long)(i0 >> 2) * 4096 + (i0 & 3) * 8;
  const bf16* gA1 = A + (long)(i1 >> 2) * 4096 + (i1 & 3) * 8;
  const bf16* gB0 = Bw + (long)(i0 >> 2) * 128 + (i0 & 3) * 8;
  const bf16* gB1 = Bw + (long)(i1 >> 2) * 128 + (i1 & 3) * 8;
  bf16* lA0 = As + i0 * 8; bf16* lA1 = As + i1 * 8;
  bf16* lB0 = Bs + i0 * 8; bf16* lB1 = Bs + i1 * 8;

  const int lane = t & 63, wv = t >> 6;
  const int moff = (wv & 1) * 64, noff = (wv >> 1) * 64;
  const int fm = lane & 15, fq = lane >> 4;

  f32x4 acc[4][4] = {};
  float dacc = 0.f;

  for (int k0 = 0; k0 < 128; k0 += 32) {
    async_copy16(gA0, lA0); async_copy16(gA1, lA1);
    async_copy16(gB0, lB0); async_copy16(gB1, lB1);
    gA0 += 32; gA1 += 32; gB0 += 32; gB1 += 32;
    __syncthreads();
    bf16x8 af[4], bfv[4];
#pragma unroll
    for (int i = 0; i < 4; ++i) {
      af[i]  = *(const bf16x8*)(As + (moff + i * 16 + fm) * 32 + fq * 8);
      bfv[i] = *(const bf16x8*)(Bs + (noff + i * 16 + fm) * 32 + fq * 8);
    }
#pragma unroll
    for (int i = 0; i < 4; ++i)
#pragma unroll
      for (int j = 0; j < 4; ++j)
        acc[i][j] = __builtin_amdgcn_mfma_f32_16x16x32_bf16(af[i], bfv[j], acc[i][j], 0, 0, 0);
    if (t < 128) {                 // den partial: row t, k-chunk k0..k0+32
#pragma unroll
      for (int c8 = 0; c8 < 4; ++c8) {
        bf16x8 q8 = *(const bf16x8*)(As + t * 32 + c8 * 8);
#pragma unroll
        for (int e = 0; e < 8; ++e) dacc += (float)q8[e] * sksum[k0 + c8 * 8 + e];
      }
    }
    __syncthreads();
  }
  if (t < 128) sden[t] = dacc * kScale + 4096.0f;

  const int c2 = lane * 2;
  const float w0[5] = {slw[0][c2], slw[1][c2], slw[2][c2], slw[3][c2], slw[4][c2]};
  const float w1[5] = {slw[0][c2+1], slw[1][c2+1], slw[2][c2+1], slw[3][c2+1], slw[4][c2+1]};
  const float lb0 = slb[c2], lb1 = slb[c2 + 1];

#pragma unroll
  for (int half = 0; half < 2; ++half) {
    if ((wv & 1) == half) {
#pragma unroll
      for (int i = 0; i < 4; ++i)
#pragma unroll
        for (int j = 0; j < 4; ++j)
#pragma unroll
          for (int r = 0; r < 4; ++r) {
            const int col = noff + j * 16 + fm;
            T[(i * 16 + fq * 4 + r) * 136 + col] = (bf16)(acc[i][j][r] * kScale + svsum[col]);
          }
    }
    __syncthreads();   // covers T (and sden on first pass)
    for (int rr = 0; rr < 16; ++rr) {
      const int lrow = wv * 16 + rr;           // 0..63
      const int row = half * 64 + lrow;        // 0..127 within tile
      const int s = (int)(m0 + row);
      const long grow = (long)b * 4096 + s;
      const float rden = 1.0f / sden[row];
      const bf16* vrow = QKVG + grow * 4096 + 2048 + h * 128 + c2;
      bf16x2 a2 = *(const bf16x2*)(T + lrow * 136 + c2);
      float lep0 = lb0, lep1 = lb1;
#pragma unroll
      for (int jt = 0; jt < 5; ++jt) {
        const int srow = s + jt - 2;
        if (srow >= 0 && srow < 4096) {        // wave-uniform branch
          bf16x2 v2 = *(const bf16x2*)(vrow + (long)(jt - 2) * 4096);
          lep0 += (float)v2[0] * w0[jt];
          lep1 += (float)v2[1] * w1[jt];
        }
      }
      bf16x2 g2 = *(const bf16x2*)(QKVG + grow * 4096 + 3072 + h * 128 + c2);
      bf16x2 o2;
      o2[0] = (bf16)(((float)a2[0] * rden + lep0) * (float)g2[0]);
      o2[1] = (bf16)(((float)a2[1] * rden + lep1) * (float)g2[1]);
      *(bf16x2*)(obuf + grow * 1024 + h * 128 + c2) = o2;
    }
    __syncthreads();
  }
}

// ---------------------------------------------------------------------------
// prep: cast X->bf16, cast/concat weights, build rope sin/cos table.
// ---------------------------------------------------------------------------
__global__ void prep_kernel(const float* __restrict__ X, const float* __restrict__ Wq,
                            const float* __restrict__ Wk, const float* __restrict__ Wv,
                            const float* __restrict__ Wg, const float* __restrict__ Wo,
                            bf16* __restrict__ Xb, bf16* __restrict__ Wcat,
                            bf16* __restrict__ Wob, float2* __restrict__ tab)
{
  const int blk = blockIdx.x;
  if (blk < 16384) {
    long g = ((long)blk * 256 + threadIdx.x) * 4;
    float4 v = *(const float4*)(X + g);
    bf16x4 o = {(bf16)v.x, (bf16)v.y, (bf16)v.z, (bf16)v.w};
    *(bf16x4*)(Xb + g) = o;
  } else if (blk < 21504) {
    long g = ((long)(blk - 16384) * 256 + threadIdx.x) * 4;
    if (g < 4194304) {
      long idx = g & 1048575;
      int sel = (int)(g >> 20);
      const float* s = sel == 0 ? Wq : sel == 1 ? Wk : sel == 2 ? Wv : Wg;
      float4 v = *(const float4*)(s + idx);
      bf16x4 o = {(bf16)v.x, (bf16)v.y, (bf16)v.z, (bf16)v.w};
      *(bf16x4*)(Wcat + g) = o;
    } else {
      long idx = g - 4194304;
      float4 v = *(const float4*)(Wo + idx);
      bf16x4 o = {(bf16)v.x, (bf16)v.y, (bf16)v.z, (bf16)v.w};
      *(bf16x4*)(Wob + idx) = o;
    }
  } else {
    int idx = (blk - 21504) * 256 + threadIdx.x;
    int s = idx >> 6, i = idx & 63;
    float inv = powf(10000.0f, -((float)(2 * i)) / 128.0f);
    float ang = (float)s * inv;
    float sn, cs;
    sincosf(ang, &sn, &cs);
    tab[idx] = make_float2(sn, cs);
  }
}

// ---------------------------------------------------------------------------
// kv via MFMA with in-LDS transpose. Grid (16, 32) = 512 blocks (2/CU).
// kvp[chunk][bh][e][d] = sum_s v[s][e] k[s][d]; + ksum/vsum partials.
// ---------------------------------------------------------------------------
__global__ __launch_bounds__(256, 2) void kv_mfma(
    const bf16* __restrict__ QKVG, float* __restrict__ kvp,
    float* __restrict__ ksump, float* __restrict__ vsump)
{
  __shared__ __align__(16) bf16 VT[128 * 40];
  __shared__ __align__(16) bf16 KT[128 * 40];
  const int t = threadIdx.x;
  const int chunk = blockIdx.x, bh = blockIdx.y;
  const int b = bh >> 3, h = bh & 7;
  const long rowbase = ((long)b * 4096 + chunk * 256) * 4096 + h * 128;
  const bf16* Kg = QKVG + rowbase + 1024;
  const bf16* Vg = QKVG + rowbase + 2048;

  const int sp = t >> 4, fc = t & 15;
  const int lane = t & 63, wv = t >> 6;
  const int eoff = (wv & 1) * 64, doff = (wv >> 1) * 64;
  const int fm = lane & 15, fq = lane >> 4;
  const int srow = t & 127;
  const bool sumK = t >= 128;

  f32x4 acc[4][4] = {};
  float rsum = 0.f;

  for (int sb = 0; sb < 256; sb += 32) {
    const long go = (long)(sb + 2 * sp) * 4096 + fc * 8;
    bf16x8 v0 = *(const bf16x8*)(Vg + go);
    bf16x8 v1 = *(const bf16x8*)(Vg + go + 4096);
    bf16x8 k0 = *(const bf16x8*)(Kg + go);
    bf16x8 k1 = *(const bf16x8*)(Kg + go + 4096);
#pragma unroll
    for (int j = 0; j < 8; ++j) {
      const int f = fc * 8 + j;
      bf16x2 vp2 = {v0[j], v1[j]};
      bf16x2 kp2 = {k0[j], k1[j]};
      *(bf16x2*)(VT + f * 40 + 2 * sp) = vp2;
      *(bf16x2*)(KT + f * 40 + 2 * sp) = kp2;
    }
    __syncthreads();
    bf16x8 af[4], bfv[4];
#pragma unroll
    for (int i = 0; i < 4; ++i) {
      af[i]  = *(const bf16x8*)(VT + (eoff + i * 16 + fm) * 40 + fq * 8);
      bfv[i] = *(const bf16x8*)(KT + (doff + i * 16 + fm) * 40 + fq * 8);
    }
#pragma unroll
    for (int i = 0; i < 4; ++i)
#pragma unroll
      for (int j = 0; j < 4; ++j)
        acc[i][j] = __builtin_amdgcn_mfma_f32_16x16x32_bf16(af[i], bfv[j], acc[i][j], 0, 0, 0);
    const bf16* rp = (sumK ? KT : VT) + srow * 40;
#pragma unroll
    for (int i = 0; i < 4; ++i) {
      bf16x8 r8 = *(const bf16x8*)(rp + i * 8);
#pragma unroll
      for (int j = 0; j < 8; ++j) rsum += (float)r8[j];
    }
    __syncthreads();
  }

  float* plane = kvp + ((long)chunk * 32 + bh) * 16384;
#pragma unroll
  for (int i = 0; i < 4; ++i)
#pragma unroll
    for (int j = 0; j < 4; ++j)
#pragma unroll
      for (int r = 0; r < 4; ++r)
        plane[(long)(eoff + i * 16 + fq * 4 + r) * 128 + (doff + j * 16 + fm)] = acc[i][j][r];
  float* sdst = (sumK ? ksump : vsump) + ((long)chunk * 32 + bh) * 128 + srow;
  *sdst = rsum;
}

// Fold 16 chunk partials -> bf16 kvT + f32 ksum/vsum.
__global__ void kv_reduce(const float* __restrict__ kvp, const float* __restrict__ ksump,
                          const float* __restrict__ vsump, bf16* __restrict__ kvT,
                          float* __restrict__ ksum, float* __restrict__ vsum)
{
  long g = (long)blockIdx.x * 256 + threadIdx.x;
  long bh = g >> 14, idx = g & 16383;
  float s = 0.f;
#pragma unroll
  for (int c = 0; c < 16; ++c) s += kvp[((long)c * 32 + bh) * 16384 + idx];
  kvT[g] = (bf16)s;
  if (g < 8192) {
    int bh2 = (int)(g >> 8), rem = (int)(g & 255), f = rem & 127;
    const float* src = (rem >> 7) ? ksump : vsump;
    float* dst = (rem >> 7) ? ksum : vsum;
    float s2 = 0.f;
#pragma unroll
    for (int c = 0; c < 16; ++c) s2 += src[((long)c * 32 + bh2) * 128 + f];
    dst[bh2 * 128 + f] = s2;
  }
}

// ---------------------------------------------------------------------------
extern "C" void kernel_launch(void* const* d_in, const int* in_sizes, int n_in,
                              void* d_out, int out_size, void* d_ws, size_t ws_size,
                              hipStream_t stream)
{
  const float* X      = (const float*)d_in[0];
  const float* Wq     = (const float*)d_in[1];
  const float* Wk     = (const float*)d_in[2];
  const float* Wv     = (const float*)d_in[3];
  const float* Wg     = (const float*)d_in[4];
  const float* Wo     = (const float*)d_in[5];
  const float* lepe_w = (const float*)d_in[6];
  const float* lepe_b = (const float*)d_in[7];
  float* out = (float*)d_out;

  char* ws = (char*)d_ws;
  bf16*   Xb    = (bf16*)(ws);
  float*  kvp   = (float*)(ws);                  // aliases Xb (dead after proj)
  bf16*   Wcat  = (bf16*)(ws + 33554432);
  bf16*   Wob   = (bf16*)(ws + 41943040);
  float2* tab   = (float2*)(ws + 44040192);
  float*  ksump = (float*)(ws + 44040192);       // aliases tab (dead after proj)
  float*  vsump = (float*)(ws + 44302336);
  bf16*   QKVG  = (bf16*)(ws + 46137344);
  float*  ksum  = (float*)(ws + 180355072);
  float*  vsum  = (float*)(ws + 180371456);
  bf16*   kvT   = (bf16*)(ws + 180387840);
  bf16*   obuf  = (bf16*)(ws + 181960704);

  prep_kernel<<<22528, 256, 0, stream>>>(X, Wq, Wk, Wv, Wg, Wo, Xb, Wcat, Wob, tab);

  gemm_qkvg<<<4096, 256, 0, stream>>>(Xb, Wcat, QKVG, tab);

  kv_mfma<<<dim3(16, 32), 256, 0, stream>>>(QKVG, kvp, ksump, vsump);
  kv_reduce<<<2048, 256, 0, stream>>>(kvp, ksump, vsump, kvT, ksum, vsum);

  gemm_num<<<dim3(32, 8, 4), 256, 0, stream>>>(QKVG, kvT, ksum, vsum, lepe_w, lepe_b, obuf);

  gemm_final<<<1024, 256, 0, stream>>>(obuf, Wob, out);
}